// Round 6
// baseline (109.649 us; speedup 1.0000x reference)
//
#include <hip/hip_runtime.h>

// SwarmNet: N=128 samples(=agents), T=100, D=4, H=32, Tp=94.
// k_conv: grid (128, 2) — unchanged from round 5 (correct, ~3 us).
// k_agg v2: grid (94, 2), 64-i tiles (188 blocks -> <=1 block/CU, no tail).
//   Phase 1 (j-loop): 8 acc/thread, ej/ei from global (VMEM, L1/L2-hot).
//   Phases 2-4: (i, d-group) ownership, b128 LDS activations, float4 global
//   weights -> LDS pipe ~6x lighter than v1.

#define NN 128
#define TT 100
#define TP 94
#define HH 32

__global__ __launch_bounds__(256) void k_conv(
    const float* __restrict__ x,
    const float* __restrict__ w1, const float* __restrict__ b1,
    const float* __restrict__ w2, const float* __restrict__ b2,
    const float* __restrict__ w3, const float* __restrict__ b3,
    const float* __restrict__ We,
    float* __restrict__ h_g, float* __restrict__ ej_g, float* __restrict__ ei_g)
{
    __shared__ float sx[4][56];    // x cols [t0g, t0g+54)
    __shared__ float s1[16][56];   // conv1 out, valid cols [0,52), pad 52..55 = 0
    __shared__ float s2[32][56];   // conv2 out, cols [0,52)
    __shared__ float s3[32][48];   // conv3 out, cols [0,48)

    const int n    = blockIdx.x;
    const int half = blockIdx.y;
    const int t0g  = half * 46;    // out t-range [t0g, t0g+48)
    const int tid  = threadIdx.x;

    if (tid < 54) {
        float4 v = ((const float4*)x)[n * TT + t0g + tid];
        sx[0][tid] = v.x; sx[1][tid] = v.y; sx[2][tid] = v.z; sx[3][tid] = v.w;
    }
    if (tid >= 64 && tid < 128) {
        int r = tid - 64;
        s1[r >> 2][52 + (r & 3)] = 0.f;
    }
    __syncthreads();

    // conv1: (4,54) -> (16,52)
    for (int idx = tid; idx < 16 * 52; idx += 256) {
        int o = idx / 52, t = idx - o * 52;
        float acc = b1[o];
        #pragma unroll
        for (int i = 0; i < 4; ++i)
            #pragma unroll
            for (int k = 0; k < 3; ++k)
                acc += sx[i][t + k] * w1[o * 12 + i * 3 + k];
        s1[o][t] = fmaxf(acc, 0.f);
    }
    __syncthreads();

    // conv2: (16,52) -> (32,52). thread = (op=tid&15, seg<13), 2 o x 4 t
    {
        const int op = tid & 15, seg = tid >> 4;
        if (seg < 13) {
            const int t0 = seg * 4;
            float acc0[4], acc1[4];
            float bv0 = b2[op], bv1 = b2[op + 16];
            #pragma unroll
            for (int u = 0; u < 4; ++u) { acc0[u] = bv0; acc1[u] = bv1; }
            #pragma unroll
            for (int i = 0; i < 16; ++i) {
                float4 f0 = *(const float4*)&s1[i][t0];
                float4 f1 = *(const float4*)&s1[i][t0 + 4];
                float a[6] = {f0.x, f0.y, f0.z, f0.w, f1.x, f1.y};
                float W00 = w2[op * 48 + i * 3 + 0];
                float W01 = w2[op * 48 + i * 3 + 1];
                float W02 = w2[op * 48 + i * 3 + 2];
                float W10 = w2[(op + 16) * 48 + i * 3 + 0];
                float W11 = w2[(op + 16) * 48 + i * 3 + 1];
                float W12 = w2[(op + 16) * 48 + i * 3 + 2];
                #pragma unroll
                for (int u = 0; u < 4; ++u) {
                    acc0[u] += a[u] * W00 + a[u + 1] * W01 + a[u + 2] * W02;
                    acc1[u] += a[u] * W10 + a[u + 1] * W11 + a[u + 2] * W12;
                }
            }
            #pragma unroll
            for (int u = 0; u < 4; ++u) {
                s2[op][t0 + u]      = fmaxf(acc0[u], 0.f);
                s2[op + 16][t0 + u] = fmaxf(acc1[u], 0.f);
            }
        }
    }
    __syncthreads();

    // conv3: (32,52) -> (32,48). thread = (op=tid&15, seg<12), 2 o x 4 t
    {
        const int op = tid & 15, seg = tid >> 4;
        if (seg < 12) {
            const int t0 = seg * 4;
            float acc0[4], acc1[4];
            float bv0 = b3[op], bv1 = b3[op + 16];
            #pragma unroll
            for (int u = 0; u < 4; ++u) { acc0[u] = bv0; acc1[u] = bv1; }
            #pragma unroll
            for (int i = 0; i < 32; ++i) {
                float4 f0 = *(const float4*)&s2[i][t0];
                float4 f1 = *(const float4*)&s2[i][t0 + 4];
                float a[6] = {f0.x, f0.y, f0.z, f0.w, f1.x, f1.y};
                float W00 = w3[op * 96 + i * 3 + 0];
                float W01 = w3[op * 96 + i * 3 + 1];
                float W02 = w3[op * 96 + i * 3 + 2];
                float W10 = w3[(op + 16) * 96 + i * 3 + 0];
                float W11 = w3[(op + 16) * 96 + i * 3 + 1];
                float W12 = w3[(op + 16) * 96 + i * 3 + 2];
                #pragma unroll
                for (int u = 0; u < 4; ++u) {
                    acc0[u] += a[u] * W00 + a[u + 1] * W01 + a[u + 2] * W02;
                    acc1[u] += a[u] * W10 + a[u + 1] * W11 + a[u + 2] * W12;
                }
            }
            #pragma unroll
            for (int u = 0; u < 4; ++u) {
                float v0 = fmaxf(acc0[u], 0.f);
                float v1 = fmaxf(acc1[u], 0.f);
                s3[op][t0 + u]      = v0;
                s3[op + 16][t0 + u] = v1;
                int tg = t0g + t0 + u;
                h_g[(tg * NN + n) * HH + op]      = v0;
                h_g[(tg * NN + n) * HH + op + 16] = v1;
            }
        }
    }
    __syncthreads();

    // proj: ej = h@We[:32], ei = h@We[32:]. thread = (dp=tid&15, seg<12), 2 d x 4 t
    {
        const int dp = tid & 15, seg = tid >> 4;
        if (seg < 12) {
            const int t0 = seg * 4;
            float aj0[4], ai0[4], aj1[4], ai1[4];
            #pragma unroll
            for (int u = 0; u < 4; ++u) { aj0[u]=0.f; ai0[u]=0.f; aj1[u]=0.f; ai1[u]=0.f; }
            #pragma unroll
            for (int c = 0; c < 32; ++c) {
                float4 f0 = *(const float4*)&s3[c][t0];
                float hv[4] = {f0.x, f0.y, f0.z, f0.w};
                float wj0 = We[c * 32 + dp];
                float wj1 = We[c * 32 + dp + 16];
                float wi0 = We[(32 + c) * 32 + dp];
                float wi1 = We[(32 + c) * 32 + dp + 16];
                #pragma unroll
                for (int u = 0; u < 4; ++u) {
                    aj0[u] += hv[u] * wj0;
                    aj1[u] += hv[u] * wj1;
                    ai0[u] += hv[u] * wi0;
                    ai1[u] += hv[u] * wi1;
                }
            }
            #pragma unroll
            for (int u = 0; u < 4; ++u) {
                int tg = t0g + t0 + u;
                ej_g[(tg * NN + n) * HH + dp]      = aj0[u];
                ej_g[(tg * NN + n) * HH + dp + 16] = aj1[u];
                ei_g[(tg * NN + n) * HH + dp]      = ai0[u];
                ei_g[(tg * NN + n) * HH + dp + 16] = ai1[u];
            }
        }
    }
}

__device__ __forceinline__ float4 relu4(float4 v) {
    return make_float4(fmaxf(v.x, 0.f), fmaxf(v.y, 0.f),
                       fmaxf(v.z, 0.f), fmaxf(v.w, 0.f));
}

__global__ __launch_bounds__(256) void k_agg(
    const float* __restrict__ x,
    const float* __restrict__ h_g, const float* __restrict__ ej_g,
    const float* __restrict__ ei_g,
    const float* __restrict__ be, const float* __restrict__ Wa,
    const float* __restrict__ ba, const float* __restrict__ Wu,
    const float* __restrict__ bu, const float* __restrict__ Wd,
    const float* __restrict__ bd, float* __restrict__ out)
{
    const int t   = blockIdx.x;  // 0..93
    const int ib  = blockIdx.y;  // 0..1 (i-slice of 64 agents)
    const int tid = threadIdx.x;

    __shared__ float sagg[64 * HH];
    __shared__ float sagg2[64 * HH];
    __shared__ float supd[64 * HH];

    const float* ejt = ej_g + t * NN * HH;          // [j][d]
    const float* eit = ei_g + (t * NN + ib * 64) * HH;  // [i_l][d]
    const float* ht  = h_g  + (t * NN + ib * 64) * HH;  // [i_l][c]

    // ---- Phase 1: agg[i,d] = sum_j relu(ej[j,d]+ei[i,d]+be[d]) - diag ----
    {
        const int d  = tid & 31;
        const int i0 = tid >> 5;   // thread owns i_l = i0 + 8u, u<8
        float bev = be[d];
        float c[8], acc[8];
        #pragma unroll
        for (int u = 0; u < 8; ++u) {
            int il = i0 + u * 8;
            c[u] = eit[il * HH + d] + bev;
            acc[u] = -fmaxf(ejt[(ib * 64 + il) * HH + d] + c[u], 0.f);
        }
        #pragma unroll 4
        for (int j = 0; j < NN; ++j) {
            float v = ejt[j * HH + d];   // coalesced 128B, L1/L2-hot
            #pragma unroll
            for (int u = 0; u < 8; ++u)
                acc[u] += fmaxf(v + c[u], 0.f);
        }
        #pragma unroll
        for (int u = 0; u < 8; ++u)
            sagg[(i0 + u * 8) * HH + d] = acc[u];
    }
    __syncthreads();

    // ---- Phase 2: agg2 = relu(agg @ Wa + ba) ----
    // thread = (dg=tid&7 -> d0=4dg, ii=tid>>3 in [0,32)), owns i = ii, ii+32
    const int dg = tid & 7;
    const int ii = tid >> 3;
    {
        const float4* Wa4 = (const float4*)Wa;       // [c][dg]
        const float4* sagg4 = (const float4*)sagg;   // [i][c4]
        float4 bav = ((const float4*)ba)[dg];
        float4 accA = bav, accB = bav;
        #pragma unroll
        for (int c4 = 0; c4 < 8; ++c4) {
            float4 aA = sagg4[ii * 8 + c4];
            float4 aB = sagg4[(ii + 32) * 8 + c4];
            float vA[4] = {aA.x, aA.y, aA.z, aA.w};
            float vB[4] = {aB.x, aB.y, aB.z, aB.w};
            #pragma unroll
            for (int m = 0; m < 4; ++m) {
                float4 w = Wa4[(c4 * 4 + m) * 8 + dg];
                accA.x += vA[m] * w.x; accA.y += vA[m] * w.y;
                accA.z += vA[m] * w.z; accA.w += vA[m] * w.w;
                accB.x += vB[m] * w.x; accB.y += vB[m] * w.y;
                accB.z += vB[m] * w.z; accB.w += vB[m] * w.w;
            }
        }
        ((float4*)sagg2)[ii * 8 + dg]        = relu4(accA);
        ((float4*)sagg2)[(ii + 32) * 8 + dg] = relu4(accB);
    }
    __syncthreads();

    // ---- Phase 3: upd = relu(h @ Wu[:32] + agg2 @ Wu[32:] + bu) ----
    {
        const float4* Wu4 = (const float4*)Wu;       // rows 0..63
        const float4* h4  = (const float4*)ht;       // [i_l][c4] global
        const float4* g4  = (const float4*)sagg2;
        float4 buv = ((const float4*)bu)[dg];
        float4 accA = buv, accB = buv;
        #pragma unroll
        for (int c4 = 0; c4 < 8; ++c4) {
            float4 hA = h4[ii * 8 + c4];
            float4 hB = h4[(ii + 32) * 8 + c4];
            float4 gA = g4[ii * 8 + c4];
            float4 gB = g4[(ii + 32) * 8 + c4];
            float vhA[4] = {hA.x, hA.y, hA.z, hA.w};
            float vhB[4] = {hB.x, hB.y, hB.z, hB.w};
            float vgA[4] = {gA.x, gA.y, gA.z, gA.w};
            float vgB[4] = {gB.x, gB.y, gB.z, gB.w};
            #pragma unroll
            for (int m = 0; m < 4; ++m) {
                float4 wh = Wu4[(c4 * 4 + m) * 8 + dg];
                float4 wg = Wu4[(32 + c4 * 4 + m) * 8 + dg];
                accA.x += vhA[m] * wh.x + vgA[m] * wg.x;
                accA.y += vhA[m] * wh.y + vgA[m] * wg.y;
                accA.z += vhA[m] * wh.z + vgA[m] * wg.z;
                accA.w += vhA[m] * wh.w + vgA[m] * wg.w;
                accB.x += vhB[m] * wh.x + vgB[m] * wg.x;
                accB.y += vhB[m] * wh.y + vgB[m] * wg.y;
                accB.z += vhB[m] * wh.z + vgB[m] * wg.z;
                accB.w += vhB[m] * wh.w + vgB[m] * wg.w;
            }
        }
        ((float4*)supd)[ii * 8 + dg]        = relu4(accA);
        ((float4*)supd)[(ii + 32) * 8 + dg] = relu4(accB);
    }
    __syncthreads();

    // ---- Phase 4: dec = upd @ Wd + bd; out = x[:,6+t,:] + dec ----
    {
        const int i  = tid >> 2;   // 0..63
        const int d4 = tid & 3;
        const float4* supd4 = (const float4*)supd;
        float a = bd[d4];
        #pragma unroll
        for (int c4 = 0; c4 < 8; ++c4) {
            float4 uu = supd4[i * 8 + c4];
            float vu[4] = {uu.x, uu.y, uu.z, uu.w};
            #pragma unroll
            for (int m = 0; m < 4; ++m)
                a += vu[m] * Wd[(c4 * 4 + m) * 4 + d4];
        }
        int n = ib * 64 + i;
        out[n * (TP * 4) + t * 4 + d4] = x[n * (TT * 4) + (6 + t) * 4 + d4] + a;
    }
}

extern "C" void kernel_launch(void* const* d_in, const int* in_sizes, int n_in,
                              void* d_out, int out_size, void* d_ws, size_t ws_size,
                              hipStream_t stream) {
    const float* x  = (const float*)d_in[0];
    const float* w1 = (const float*)d_in[1];
    const float* b1 = (const float*)d_in[2];
    const float* w2 = (const float*)d_in[3];
    const float* b2 = (const float*)d_in[4];
    const float* w3 = (const float*)d_in[5];
    const float* b3 = (const float*)d_in[6];
    const float* We = (const float*)d_in[7];
    const float* be = (const float*)d_in[8];
    const float* Wa = (const float*)d_in[9];
    const float* ba = (const float*)d_in[10];
    const float* Wu = (const float*)d_in[11];
    const float* bu = (const float*)d_in[12];
    const float* Wd = (const float*)d_in[13];
    const float* bd = (const float*)d_in[14];

    float* ws   = (float*)d_ws;
    float* h_g  = ws;                      // 94*128*32
    float* ej_g = ws + TP * NN * HH;       // 94*128*32
    float* ei_g = ws + 2 * TP * NN * HH;   // 94*128*32

    k_conv<<<dim3(NN, 2), 256, 0, stream>>>(x, w1, b1, w2, b2, w3, b3, We,
                                            h_g, ej_g, ei_g);
    k_agg<<<dim3(TP, 2), 256, 0, stream>>>(x, h_g, ej_g, ei_g,
                                           be, Wa, ba, Wu, bu, Wd, bd,
                                           (float*)d_out);
}

// Round 7
// 101.787 us; speedup vs baseline: 1.0772x; 1.0772x over previous
//
#include <hip/hip_runtime.h>

// SwarmNet: N=128 samples(=agents), T=100, D=4, H=32, Tp=94.
// Round-7 = round-2 (measured best, 102.8us) with one fix: h_g stored directly
// from conv3 registers (removes the 16-way bank-conflicted s3 transpose loop).
// k_conv: grid (128, 2). Block = (sample n, t-half), out t-range [half*46, +48).
// k_agg:  grid (94, 4). Pairwise relu-sum aggregation + Wa/Wu/Wd matmuls + residual.

#define NN 128
#define TT 100
#define TP 94
#define HH 32

__global__ __launch_bounds__(256) void k_conv(
    const float* __restrict__ x,
    const float* __restrict__ w1, const float* __restrict__ b1,
    const float* __restrict__ w2, const float* __restrict__ b2,
    const float* __restrict__ w3, const float* __restrict__ b3,
    const float* __restrict__ We,
    float* __restrict__ h_g, float* __restrict__ ej_g, float* __restrict__ ei_g)
{
    __shared__ float sx[4][72];    // x cols [t0g, t0g+54), zero-padded to 72
    __shared__ float s1[16][68];   // conv1 out (valid t<52)
    __shared__ float s2[32][64];   // conv2 out (valid t<50)
    __shared__ float s3[32][48];   // conv3 out (valid t<48)

    const int n    = blockIdx.x;
    const int half = blockIdx.y;
    const int t0g  = half * 46;    // out t-range [t0g, t0g+48); halves overlap at 46,47
    const int tid  = threadIdx.x;

    // stage x: 54 float4 columns; zero-fill pad columns
    if (tid < 72) {
        float4 v = make_float4(0.f, 0.f, 0.f, 0.f);
        if (tid < 54) v = ((const float4*)x)[n * TT + t0g + tid];
        sx[0][tid] = v.x; sx[1][tid] = v.y; sx[2][tid] = v.z; sx[3][tid] = v.w;
    }
    __syncthreads();

    // conv1: (4,·) -> (16,·), 16*68 outputs, flat
    for (int idx = tid; idx < 16 * 68; idx += 256) {
        int o = idx / 68, t = idx - o * 68;
        float acc = b1[o];
        #pragma unroll
        for (int i = 0; i < 4; ++i)
            #pragma unroll
            for (int k = 0; k < 3; ++k)
                acc += sx[i][t + k] * w1[o * 12 + i * 3 + k];
        s1[o][t] = fmaxf(acc, 0.f);
    }
    __syncthreads();

    // conv2: (16,·) -> (32,·). thread = (o=tid&31, seg=tid>>5), 8 t each, t0=seg*8
    {
        const int o = tid & 31, seg = tid >> 5;
        const int t0 = seg * 8;
        float acc[8];
        float bv = b2[o];
        #pragma unroll
        for (int u = 0; u < 8; ++u) acc[u] = bv;
        #pragma unroll
        for (int i = 0; i < 16; ++i) {
            float4 f0 = *(const float4*)&s1[i][t0];
            float4 f1 = *(const float4*)&s1[i][t0 + 4];
            float4 f2 = *(const float4*)&s1[i][t0 + 8];
            float a[12] = {f0.x, f0.y, f0.z, f0.w, f1.x, f1.y, f1.z, f1.w,
                           f2.x, f2.y, f2.z, f2.w};
            float W0 = w2[o * 48 + i * 3 + 0];
            float W1 = w2[o * 48 + i * 3 + 1];
            float W2 = w2[o * 48 + i * 3 + 2];
            #pragma unroll
            for (int u = 0; u < 8; ++u)
                acc[u] += a[u] * W0 + a[u + 1] * W1 + a[u + 2] * W2;
        }
        #pragma unroll
        for (int u = 0; u < 8; ++u) s2[o][t0 + u] = fmaxf(acc[u], 0.f);
    }
    __syncthreads();

    // conv3: (32,·) -> (32,48). thread = (o=tid&31, seg=tid>>5<6), 8 t each.
    // Writes s3 (for proj) and h_g directly from registers (coalesced 128B runs).
    {
        const int o = tid & 31, seg = tid >> 5;
        if (seg < 6) {
            const int t0 = seg * 8;
            float acc[8];
            float bv = b3[o];
            #pragma unroll
            for (int u = 0; u < 8; ++u) acc[u] = bv;
            #pragma unroll
            for (int i = 0; i < 32; ++i) {
                float4 f0 = *(const float4*)&s2[i][t0];
                float4 f1 = *(const float4*)&s2[i][t0 + 4];
                float4 f2 = *(const float4*)&s2[i][t0 + 8];
                float a[12] = {f0.x, f0.y, f0.z, f0.w, f1.x, f1.y, f1.z, f1.w,
                               f2.x, f2.y, f2.z, f2.w};
                float W0 = w3[o * 96 + i * 3 + 0];
                float W1 = w3[o * 96 + i * 3 + 1];
                float W2 = w3[o * 96 + i * 3 + 2];
                #pragma unroll
                for (int u = 0; u < 8; ++u)
                    acc[u] += a[u] * W0 + a[u + 1] * W1 + a[u + 2] * W2;
            }
            #pragma unroll
            for (int u = 0; u < 8; ++u) {
                float v = fmaxf(acc[u], 0.f);
                s3[o][t0 + u] = v;
                h_g[((t0g + t0 + u) * NN + n) * HH + o] = v;
            }
        }
    }
    __syncthreads();

    // proj: ej = h@We[:32], ei = h@We[32:]. thread = (d=tid&31, seg=tid>>5<6), 8 t
    {
        const int d = tid & 31, seg = tid >> 5;
        if (seg < 6) {
            const int t0 = seg * 8;
            float aj[8], ai[8];
            #pragma unroll
            for (int u = 0; u < 8; ++u) { aj[u] = 0.f; ai[u] = 0.f; }
            #pragma unroll
            for (int c = 0; c < 32; ++c) {
                float4 f0 = *(const float4*)&s3[c][t0];
                float4 f1 = *(const float4*)&s3[c][t0 + 4];
                float hv[8] = {f0.x, f0.y, f0.z, f0.w, f1.x, f1.y, f1.z, f1.w};
                float wj = We[c * 32 + d];
                float wi = We[(32 + c) * 32 + d];
                #pragma unroll
                for (int u = 0; u < 8; ++u) {
                    aj[u] += hv[u] * wj;
                    ai[u] += hv[u] * wi;
                }
            }
            #pragma unroll
            for (int u = 0; u < 8; ++u) {
                int tg = t0g + t0 + u;
                ej_g[(tg * NN + n) * HH + d] = aj[u];
                ei_g[(tg * NN + n) * HH + d] = ai[u];
            }
        }
    }
}

__global__ __launch_bounds__(256) void k_agg(
    const float* __restrict__ x,
    const float* __restrict__ h_g, const float* __restrict__ ej_g,
    const float* __restrict__ ei_g,
    const float* __restrict__ be, const float* __restrict__ Wa,
    const float* __restrict__ ba, const float* __restrict__ Wu,
    const float* __restrict__ bu, const float* __restrict__ Wd,
    const float* __restrict__ bd, float* __restrict__ out)
{
    const int t  = blockIdx.x;  // 0..93
    const int ib = blockIdx.y;  // 0..3 (i-slice of 32 agents)
    const int tid = threadIdx.x;

    __shared__ float sej[NN * HH];
    __shared__ float sei[32 * HH];
    __shared__ float sh[32 * HH];
    __shared__ float sagg[32 * HH];
    __shared__ float sagg2[32 * HH];
    __shared__ float supd[32 * HH];

    // stage ej[t,:,:] (16 KB) + ei/h slices, vectorized
    {
        const float4* ej4 = (const float4*)(ej_g + t * NN * HH);
        float4* s4 = (float4*)sej;
        #pragma unroll
        for (int u = 0; u < 4; ++u) s4[tid + 256 * u] = ej4[tid + 256 * u];
        const float4* ei4 = (const float4*)(ei_g + (t * NN + ib * 32) * HH);
        const float4* h4  = (const float4*)(h_g  + (t * NN + ib * 32) * HH);
        ((float4*)sei)[tid] = ei4[tid];
        ((float4*)sh)[tid]  = h4[tid];
    }
    __syncthreads();

    const int d  = tid & 31;
    const int i0 = tid >> 5;  // thread owns i = i0 + 8u, u<4

    // agg[i,d] = sum_j relu(ej[j,d] + ei[i,d] + be[d]) - diag
    {
        float bev = be[d];
        float c[4], acc[4];
        #pragma unroll
        for (int u = 0; u < 4; ++u) {
            int i = i0 + u * 8;
            c[u] = sei[i * HH + d] + bev;
            acc[u] = -fmaxf(sej[(ib * 32 + i) * HH + d] + c[u], 0.f);
        }
        #pragma unroll 8
        for (int j = 0; j < NN; ++j) {
            float v = sej[j * HH + d];   // broadcast across lanes sharing d
            #pragma unroll
            for (int u = 0; u < 4; ++u)
                acc[u] += fmaxf(v + c[u], 0.f);
        }
        #pragma unroll
        for (int u = 0; u < 4; ++u)
            sagg[(i0 + u * 8) * HH + d] = acc[u];
    }
    __syncthreads();

    // agg2 = relu(agg @ Wa + ba)
    {
        float acc[4];
        float bav = ba[d];
        #pragma unroll
        for (int u = 0; u < 4; ++u) acc[u] = bav;
        #pragma unroll
        for (int c = 0; c < 32; ++c) {
            float wa = Wa[c * 32 + d];
            #pragma unroll
            for (int u = 0; u < 4; ++u)
                acc[u] += sagg[(i0 + u * 8) * HH + c] * wa;
        }
        #pragma unroll
        for (int u = 0; u < 4; ++u)
            sagg2[(i0 + u * 8) * HH + d] = fmaxf(acc[u], 0.f);
    }
    __syncthreads();

    // upd = relu(h @ Wu[:32] + agg2 @ Wu[32:] + bu)
    {
        float acc[4];
        float buv = bu[d];
        #pragma unroll
        for (int u = 0; u < 4; ++u) acc[u] = buv;
        #pragma unroll
        for (int c = 0; c < 32; ++c) {
            float wh = Wu[c * 32 + d];
            float wg = Wu[(32 + c) * 32 + d];
            #pragma unroll
            for (int u = 0; u < 4; ++u) {
                int i = i0 + u * 8;
                acc[u] += sh[i * HH + c] * wh + sagg2[i * HH + c] * wg;
            }
        }
        #pragma unroll
        for (int u = 0; u < 4; ++u)
            supd[(i0 + u * 8) * HH + d] = fmaxf(acc[u], 0.f);
    }
    __syncthreads();

    // dec = upd @ Wd + bd; out[n,t,:] = x[n,6+t,:] + dec
    if (tid < 128) {
        int i = tid >> 2, d4 = tid & 3;
        int n = ib * 32 + i;
        float a = bd[d4];
        #pragma unroll
        for (int c = 0; c < 32; ++c)
            a += supd[i * HH + c] * Wd[c * 4 + d4];
        out[n * (TP * 4) + t * 4 + d4] = x[n * (TT * 4) + (6 + t) * 4 + d4] + a;
    }
}

extern "C" void kernel_launch(void* const* d_in, const int* in_sizes, int n_in,
                              void* d_out, int out_size, void* d_ws, size_t ws_size,
                              hipStream_t stream) {
    const float* x  = (const float*)d_in[0];
    const float* w1 = (const float*)d_in[1];
    const float* b1 = (const float*)d_in[2];
    const float* w2 = (const float*)d_in[3];
    const float* b2 = (const float*)d_in[4];
    const float* w3 = (const float*)d_in[5];
    const float* b3 = (const float*)d_in[6];
    const float* We = (const float*)d_in[7];
    const float* be = (const float*)d_in[8];
    const float* Wa = (const float*)d_in[9];
    const float* ba = (const float*)d_in[10];
    const float* Wu = (const float*)d_in[11];
    const float* bu = (const float*)d_in[12];
    const float* Wd = (const float*)d_in[13];
    const float* bd = (const float*)d_in[14];

    float* ws   = (float*)d_ws;
    float* h_g  = ws;                      // 94*128*32
    float* ej_g = ws + TP * NN * HH;       // 94*128*32
    float* ei_g = ws + 2 * TP * NN * HH;   // 94*128*32

    k_conv<<<dim3(NN, 2), 256, 0, stream>>>(x, w1, b1, w2, b2, w3, b3, We,
                                            h_g, ej_g, ei_g);
    k_agg<<<dim3(TP, 4), 256, 0, stream>>>(x, h_g, ej_g, ei_g,
                                           be, Wa, ba, Wu, bu, Wd, bd,
                                           (float*)d_out);
}